// Round 1
// baseline (336.541 us; speedup 1.0000x reference)
//
#include <hip/hip_runtime.h>

#define SDIM 8192
#define RAD  256     // WINDOW_SIZE/2
#define GTOK 64
#define KSEL 8

// ---------------------------------------------------------------- top-8 per row
__global__ __launch_bounds__(256) void topk_kernel(const float* __restrict__ scores,
                                                   int* __restrict__ rand_idx) {
    __shared__ float cv[2048];
    __shared__ int   ci[2048];
    const int row = blockIdx.x;
    const int t   = threadIdx.x;
    const float4* rowp = reinterpret_cast<const float4*>(scores + (size_t)row * SDIM);

    float v[KSEL]; int ix[KSEL];
#pragma unroll
    for (int q = 0; q < KSEL; q++) { v[q] = -INFINITY; ix[q] = 0x7fffffff; }

    // thread t loads float4 indices t + k*256 (fully coalesced), 32 values total
    for (int k = 0; k < 8; k++) {
        int f4 = t + k * 256;
        float4 d = rowp[f4];
        int jb = f4 * 4;
        float vals[4] = {d.x, d.y, d.z, d.w};
#pragma unroll
        for (int e = 0; e < 4; e++) {
            float val = vals[e];
            int j = jb + e;
            if (val > v[KSEL - 1]) {
                // unrolled swap-chain insertion (static indices -> stays in registers)
#pragma unroll
                for (int q = 0; q < KSEL; q++) {
                    if (val > v[q]) {
                        float tv = v[q]; int ti = ix[q];
                        v[q] = val; ix[q] = j;
                        val = tv; j = ti;
                    }
                }
            }
        }
    }
#pragma unroll
    for (int q = 0; q < KSEL; q++) { cv[t * KSEL + q] = v[q]; ci[t * KSEL + q] = ix[q]; }
    __syncthreads();

    // single-wave extraction of global top-8 among 2048 candidates
    if (t < 64) {
        for (int round = 0; round < KSEL; round++) {
            float bv = -INFINITY; int bi = 0x7fffffff;
            for (int e = 0; e < 32; e++) {
                int c = t * 32 + e;
                float val = cv[c]; int id = ci[c];
                if (val > bv || (val == bv && id < bi)) { bv = val; bi = id; }
            }
#pragma unroll
            for (int s = 32; s > 0; s >>= 1) {
                float ov = __shfl_down(bv, s);
                int   oi = __shfl_down(bi, s);
                if (ov > bv || (ov == bv && oi < bi)) { bv = ov; bi = oi; }
            }
            bi = __shfl(bi, 0);   // broadcast winner index
            for (int e = 0; e < 32; e++) {
                int c = t * 32 + e;
                if (ci[c] == bi) cv[c] = -INFINITY;   // consume winner
            }
            if (t == 0) rand_idx[row * KSEL + round] = bi;
        }
    }
}

// ------------------------------------- counts (analytic) + scan -> offsets etc.
__global__ __launch_bounds__(1024) void scan_kernel(const int* __restrict__ rand_idx,
                                                    int* __restrict__ offsets,
                                                    float* __restrict__ out_off,
                                                    float* __restrict__ out_cnt,
                                                    float* __restrict__ out_sparsity) {
    __shared__ int part[1024];
    const int t = threadIdx.x;
    const int base = t * 8;
    int local[8], cnts[8];
    int sum = 0;
#pragma unroll
    for (int e = 0; e < 8; e++) {
        const int i = base + e;
        int cnt;
        if (i < GTOK) {
            cnt = SDIM;                       // global row: fully connected
        } else {
            int wlo = i - RAD; if (wlo < 0) wlo = 0;
            int whi = i + RAD; if (whi > SDIM - 1) whi = SDIM - 1;
            cnt = (whi - wlo + 1) + (wlo < GTOK ? wlo : GTOK);  // band + global cols outside band
#pragma unroll
            for (int q = 0; q < KSEL; q++) {
                int r = rand_idx[i * KSEL + q];
                if (r >= GTOK && (r < wlo || r > whi)) cnt++;   // uncovered random col
            }
        }
        cnts[e] = cnt;
        local[e] = sum;
        sum += cnt;
    }
    part[t] = sum;
    __syncthreads();
    for (int d = 1; d < 1024; d <<= 1) {
        int add = (t >= d) ? part[t - d] : 0;
        __syncthreads();
        part[t] += add;
        __syncthreads();
    }
    const int excl = (t == 0) ? 0 : part[t - 1];
#pragma unroll
    for (int e = 0; e < 8; e++) {
        int off = excl + local[e];
        offsets[base + e] = off;
        out_off[base + e] = (float)off;
        out_cnt[base + e] = (float)cnts[e];
    }
    if (t == 1023) {
        int total = excl + local[7] + cnts[7];
        offsets[SDIM] = total;
        out_off[SDIM] = (float)total;
        *out_sparsity = (float)total / 67108864.0f;   // total < 2^24 -> exact
    }
}

// ----------------------------------------------- mask floats + col_indices fill
__global__ __launch_bounds__(256) void fill_kernel(const int* __restrict__ rand_idx,
                                                   const int* __restrict__ offsets,
                                                   float* __restrict__ mask_out,
                                                   float* __restrict__ col_out) {
    __shared__ int cs[256];
    const int row = blockIdx.x;
    const int t   = threadIdx.x;
    int r[KSEL];
#pragma unroll
    for (int q = 0; q < KSEL; q++) r[q] = rand_idx[row * KSEL + q];
    const bool full = row < GTOK;
    int wlo = row - RAD; if (wlo < 0) wlo = 0;
    int whi = row + RAD; if (whi > SDIM - 1) whi = SDIM - 1;

    // mask: coalesced float4 writes
    float4* mrow = reinterpret_cast<float4*>(mask_out + (size_t)row * SDIM);
    for (int k = 0; k < 8; k++) {
        int f4 = t + k * 256;
        int jb = f4 * 4;
        float4 o;
        float* op = &o.x;
#pragma unroll
        for (int e = 0; e < 4; e++) {
            int j = jb + e;
            bool b = full || (j < GTOK) || (j >= wlo && j <= whi);
#pragma unroll
            for (int q = 0; q < KSEL; q++) b = b || (j == r[q]);
            op[e] = b ? 1.0f : 0.0f;
        }
        mrow[f4] = o;
    }

    // col_indices: each thread owns 32 contiguous columns -> bitmask + block scan
    unsigned int bm = 0;
    const int jb = t * 32;
#pragma unroll
    for (int e = 0; e < 32; e++) {
        int j = jb + e;
        bool b = full || (j < GTOK) || (j >= wlo && j <= whi);
#pragma unroll
        for (int q = 0; q < KSEL; q++) b = b || (j == r[q]);
        bm |= (b ? 1u : 0u) << e;
    }
    cs[t] = __popc(bm);
    __syncthreads();
    for (int d = 1; d < 256; d <<= 1) {
        int add = (t >= d) ? cs[t - d] : 0;
        __syncthreads();
        cs[t] += add;
        __syncthreads();
    }
    int pos = offsets[row] + ((t == 0) ? 0 : cs[t - 1]);
    for (int e = 0; e < 32; e++) {
        if ((bm >> e) & 1u) col_out[pos++] = (float)(jb + e);
    }
}

extern "C" void kernel_launch(void* const* d_in, const int* in_sizes, int n_in,
                              void* d_out, int out_size, void* d_ws, size_t ws_size,
                              hipStream_t stream) {
    const float* scores = (const float*)d_in[1];   // rand_scores [S,S] f32

    float* out_f    = (float*)d_out;
    float* mask_out = out_f;                                   // S*S
    float* off_out  = out_f + (size_t)SDIM * SDIM;             // S+1
    float* col_out  = off_out + (SDIM + 1);                    // TC
    const long long TC = (long long)out_size
                       - ((long long)SDIM * SDIM + (SDIM + 1) + SDIM + 1);
    float* cnt_out = col_out + TC;                             // S
    float* sp_out  = cnt_out + SDIM;                           // 1

    int* rand_idx = (int*)d_ws;                  // S*K ints
    int* offsets  = rand_idx + SDIM * KSEL;      // S+1 ints

    topk_kernel<<<SDIM, 256, 0, stream>>>(scores, rand_idx);
    scan_kernel<<<1, 1024, 0, stream>>>(rand_idx, offsets, off_out, cnt_out, sp_out);
    fill_kernel<<<SDIM, 256, 0, stream>>>(rand_idx, offsets, mask_out, col_out);
}

// Round 2
// 169.413 us; speedup vs baseline: 1.9865x; 1.9865x over previous
//
#include <hip/hip_runtime.h>

#define SDIM 8192
#define RAD  256     // WINDOW_SIZE/2
#define GTOK 64
#define KSEL 8
#define CAP  768
#define THRESH 2.2f  // P(N(0,1) > 2.2) = 1.39% -> ~114 candidates/row (sigma ~10.6)

// --------------------------------------------------- threshold-filtered top-8
__global__ __launch_bounds__(256) void topk_kernel(const float* __restrict__ scores,
                                                   int* __restrict__ rand_idx,
                                                   int* __restrict__ flags) {
    __shared__ float cand_v[CAP];
    __shared__ int   cand_i[CAP];
    __shared__ int   cnt;
    const int row = blockIdx.x;
    const int t   = threadIdx.x;
    if (t == 0) cnt = 0;
    __syncthreads();

    const float4* rowp = reinterpret_cast<const float4*>(scores + (size_t)row * SDIM);
    for (int k = 0; k < 8; k++) {
        int f4 = t + k * 256;              // fully coalesced
        float4 d = rowp[f4];
        int jb = f4 * 4;
        if (d.x > THRESH) { int p = atomicAdd(&cnt, 1); if (p < CAP) { cand_v[p] = d.x; cand_i[p] = jb;     } }
        if (d.y > THRESH) { int p = atomicAdd(&cnt, 1); if (p < CAP) { cand_v[p] = d.y; cand_i[p] = jb + 1; } }
        if (d.z > THRESH) { int p = atomicAdd(&cnt, 1); if (p < CAP) { cand_v[p] = d.z; cand_i[p] = jb + 2; } }
        if (d.w > THRESH) { int p = atomicAdd(&cnt, 1); if (p < CAP) { cand_v[p] = d.w; cand_i[p] = jb + 3; } }
    }
    __syncthreads();

    const int n = cnt;
    if (t == 0) flags[row] = (n < KSEL || n > CAP) ? 1 : 0;
    if (n < KSEL || n > CAP) return;       // exact fallback kernel handles this row

    // single-wave exact top-8 among n candidates (candidate SET is deterministic;
    // selection is order-independent: argmax with tie-break to lower index)
    if (t < 64) {
        for (int round = 0; round < KSEL; round++) {
            float bv = -INFINITY; int bi = 0x7fffffff;
            for (int c = t; c < n; c += 64) {           // consecutive -> conflict-free
                float val = cand_v[c]; int id = cand_i[c];
                if (val > bv || (val == bv && id < bi)) { bv = val; bi = id; }
            }
#pragma unroll
            for (int s = 32; s > 0; s >>= 1) {
                float ov = __shfl_down(bv, s);
                int   oi = __shfl_down(bi, s);
                if (ov > bv || (ov == bv && oi < bi)) { bv = ov; bi = oi; }
            }
            bi = __shfl(bi, 0);
            for (int c = t; c < n; c += 64) if (cand_i[c] == bi) cand_v[c] = -INFINITY;
            if (t == 0) rand_idx[row * KSEL + round] = bi;
        }
    }
}

// ------------------------------- exact fallback for flagged rows (never fires
// for the fixed input, but guarantees data-independent correctness)
__global__ __launch_bounds__(64) void fallback_kernel(const float* __restrict__ scores,
                                                      int* __restrict__ rand_idx,
                                                      const int* __restrict__ flags) {
    const int base = blockIdx.x * 64;
    const int t = threadIdx.x;
    unsigned long long m = __ballot(flags[base + t] != 0);
    if (m == 0ull) return;
    if (t == 0) {
        for (int b = 0; b < 64; b++) if ((m >> b) & 1ull) {
            const int row = base + b;
            const float* rp = scores + (size_t)row * SDIM;
            int chosen[KSEL];
            for (int round = 0; round < KSEL; round++) {
                float bv = -INFINITY; int bi = 0x7fffffff;
                for (int j = 0; j < SDIM; j++) {
                    bool used = false;
                    for (int q = 0; q < round; q++) used = used || (chosen[q] == j);
                    float val = rp[j];
                    if (!used && val > bv) { bv = val; bi = j; }  // ties -> lowest index
                }
                chosen[round] = bi;
                rand_idx[row * KSEL + round] = bi;
            }
        }
    }
}

// ------------------------------------- counts (analytic) + scan -> offsets etc.
__global__ __launch_bounds__(1024) void scan_kernel(const int* __restrict__ rand_idx,
                                                    int* __restrict__ offsets,
                                                    float* __restrict__ out_off,
                                                    float* __restrict__ out_cnt,
                                                    float* __restrict__ out_sparsity) {
    __shared__ int part[1024];
    const int t = threadIdx.x;
    const int base = t * 8;
    int local[8], cnts[8];
    int sum = 0;
#pragma unroll
    for (int e = 0; e < 8; e++) {
        const int i = base + e;
        int cnt;
        if (i < GTOK) {
            cnt = SDIM;                       // global row: fully connected
        } else {
            int wlo = i - RAD; if (wlo < 0) wlo = 0;
            int whi = i + RAD; if (whi > SDIM - 1) whi = SDIM - 1;
            cnt = (whi - wlo + 1) + (wlo < GTOK ? wlo : GTOK);  // band + global cols outside band
#pragma unroll
            for (int q = 0; q < KSEL; q++) {
                int r = rand_idx[i * KSEL + q];
                if (r >= GTOK && (r < wlo || r > whi)) cnt++;   // uncovered random col
            }
        }
        cnts[e] = cnt;
        local[e] = sum;
        sum += cnt;
    }
    part[t] = sum;
    __syncthreads();
    for (int d = 1; d < 1024; d <<= 1) {
        int add = (t >= d) ? part[t - d] : 0;
        __syncthreads();
        part[t] += add;
        __syncthreads();
    }
    const int excl = (t == 0) ? 0 : part[t - 1];
#pragma unroll
    for (int e = 0; e < 8; e++) {
        int off = excl + local[e];
        offsets[base + e] = off;
        out_off[base + e] = (float)off;
        out_cnt[base + e] = (float)cnts[e];
    }
    if (t == 1023) {
        int total = excl + local[7] + cnts[7];
        offsets[SDIM] = total;
        out_off[SDIM] = (float)total;
        *out_sparsity = (float)total / 67108864.0f;   // total < 2^24 -> exact
    }
}

// ----------------------------------------------- mask floats + col_indices fill
__global__ __launch_bounds__(256) void fill_kernel(const int* __restrict__ rand_idx,
                                                   const int* __restrict__ offsets,
                                                   float* __restrict__ mask_out,
                                                   float* __restrict__ col_out) {
    __shared__ int cs[256];
    const int row = blockIdx.x;
    const int t   = threadIdx.x;
    int r[KSEL];
#pragma unroll
    for (int q = 0; q < KSEL; q++) r[q] = rand_idx[row * KSEL + q];
    const bool full = row < GTOK;
    int wlo = row - RAD; if (wlo < 0) wlo = 0;
    int whi = row + RAD; if (whi > SDIM - 1) whi = SDIM - 1;

    // mask: coalesced float4 writes
    float4* mrow = reinterpret_cast<float4*>(mask_out + (size_t)row * SDIM);
    for (int k = 0; k < 8; k++) {
        int f4 = t + k * 256;
        int jb = f4 * 4;
        float4 o;
        float* op = &o.x;
#pragma unroll
        for (int e = 0; e < 4; e++) {
            int j = jb + e;
            bool b = full || (j < GTOK) || (j >= wlo && j <= whi);
#pragma unroll
            for (int q = 0; q < KSEL; q++) b = b || (j == r[q]);
            op[e] = b ? 1.0f : 0.0f;
        }
        mrow[f4] = o;
    }

    // col_indices: each thread owns 32 contiguous columns -> bitmask + block scan
    unsigned int bm = 0;
    const int jb = t * 32;
#pragma unroll
    for (int e = 0; e < 32; e++) {
        int j = jb + e;
        bool b = full || (j < GTOK) || (j >= wlo && j <= whi);
#pragma unroll
        for (int q = 0; q < KSEL; q++) b = b || (j == r[q]);
        bm |= (b ? 1u : 0u) << e;
    }
    cs[t] = __popc(bm);
    __syncthreads();
    for (int d = 1; d < 256; d <<= 1) {
        int add = (t >= d) ? cs[t - d] : 0;
        __syncthreads();
        cs[t] += add;
        __syncthreads();
    }
    int pos = offsets[row] + ((t == 0) ? 0 : cs[t - 1]);
    for (int e = 0; e < 32; e++) {
        if ((bm >> e) & 1u) col_out[pos++] = (float)(jb + e);
    }
}

extern "C" void kernel_launch(void* const* d_in, const int* in_sizes, int n_in,
                              void* d_out, int out_size, void* d_ws, size_t ws_size,
                              hipStream_t stream) {
    const float* scores = (const float*)d_in[1];   // rand_scores [S,S] f32

    float* out_f    = (float*)d_out;
    float* mask_out = out_f;                                   // S*S
    float* off_out  = out_f + (size_t)SDIM * SDIM;             // S+1
    float* col_out  = off_out + (SDIM + 1);                    // TC
    const long long TC = (long long)out_size
                       - ((long long)SDIM * SDIM + (SDIM + 1) + SDIM + 1);
    float* cnt_out = col_out + TC;                             // S
    float* sp_out  = cnt_out + SDIM;                           // 1

    int* rand_idx = (int*)d_ws;                  // S*K ints
    int* offsets  = rand_idx + SDIM * KSEL;      // S+1 ints
    int* flags    = offsets + (SDIM + 1);        // S ints

    topk_kernel<<<SDIM, 256, 0, stream>>>(scores, rand_idx, flags);
    fallback_kernel<<<SDIM / 64, 64, 0, stream>>>(scores, rand_idx, flags);
    scan_kernel<<<1, 1024, 0, stream>>>(rand_idx, offsets, off_out, cnt_out, sp_out);
    fill_kernel<<<SDIM, 256, 0, stream>>>(rand_idx, offsets, mask_out, col_out);
}

// Round 3
// 148.884 us; speedup vs baseline: 2.2604x; 1.1379x over previous
//
#include <hip/hip_runtime.h>

#define SDIM 8192
#define RAD  256     // WINDOW_SIZE/2
#define GTOK 64
#define KSEL 8
#define CAP  768
#define THRESH 2.2f  // P(N(0,1)>2.2)=1.39% -> ~114 candidates/row; [8,768] is >30 sigma safe

// --------------- fused: threshold top-8 + mask row write + analytic row count
__global__ __launch_bounds__(256) void fused_kernel(const float* __restrict__ scores,
                                                    int* __restrict__ rand_idx,
                                                    int* __restrict__ flags,
                                                    int* __restrict__ counts,
                                                    float* __restrict__ out_cnt,
                                                    float* __restrict__ mask_out) {
    __shared__ float cand_v[CAP];
    __shared__ int   cand_i[CAP];
    __shared__ int   top8[KSEL];
    __shared__ int   cnt;
    const int row = blockIdx.x;
    const int t   = threadIdx.x;
    if (t == 0) cnt = 0;
    __syncthreads();

    // load whole row (8 float4/thread, coalesced) then filter
    const float4* rowp = reinterpret_cast<const float4*>(scores + (size_t)row * SDIM);
    float4 d[8];
#pragma unroll
    for (int k = 0; k < 8; k++) d[k] = rowp[t + k * 256];
#pragma unroll
    for (int k = 0; k < 8; k++) {
        int jb = (t + k * 256) * 4;
        if (d[k].x > THRESH) { int p = atomicAdd(&cnt, 1); if (p < CAP) { cand_v[p] = d[k].x; cand_i[p] = jb;     } }
        if (d[k].y > THRESH) { int p = atomicAdd(&cnt, 1); if (p < CAP) { cand_v[p] = d[k].y; cand_i[p] = jb + 1; } }
        if (d[k].z > THRESH) { int p = atomicAdd(&cnt, 1); if (p < CAP) { cand_v[p] = d[k].z; cand_i[p] = jb + 2; } }
        if (d[k].w > THRESH) { int p = atomicAdd(&cnt, 1); if (p < CAP) { cand_v[p] = d[k].w; cand_i[p] = jb + 3; } }
    }
    __syncthreads();

    const int n = cnt;
    const bool bad = (n < KSEL || n > CAP);
    if (t == 0) flags[row] = bad ? 1 : 0;
    if (bad) return;   // fallback kernel rewrites rand_idx + mask row + count

    // single-wave exact top-8 of the candidate SET (order-independent: argmax
    // with tie-break to lower index)
    if (t < 64) {
        for (int round = 0; round < KSEL; round++) {
            float bv = -INFINITY; int bi = 0x7fffffff;
            for (int c = t; c < n; c += 64) {
                float val = cand_v[c]; int id = cand_i[c];
                if (val > bv || (val == bv && id < bi)) { bv = val; bi = id; }
            }
#pragma unroll
            for (int s = 32; s > 0; s >>= 1) {
                float ov = __shfl_down(bv, s);
                int   oi = __shfl_down(bi, s);
                if (ov > bv || (ov == bv && oi < bi)) { bv = ov; bi = oi; }
            }
            bi = __shfl(bi, 0);
            for (int c = t; c < n; c += 64) if (cand_i[c] == bi) cand_v[c] = -INFINITY;
            if (t == 0) { top8[round] = bi; rand_idx[row * KSEL + round] = bi; }
        }
    }
    __syncthreads();

    int wlo = row - RAD; if (wlo < 0) wlo = 0;
    int whi = row + RAD; if (whi > SDIM - 1) whi = SDIM - 1;
    const bool full = row < GTOK;

    // analytic count (thread 0)
    if (t == 0) {
        int c;
        if (full) c = SDIM;
        else {
            c = (whi - wlo + 1) + (wlo < GTOK ? wlo : GTOK);
#pragma unroll
            for (int q = 0; q < KSEL; q++) {
                int r = top8[q];
                if (r >= GTOK && (r < wlo || r > whi)) c++;
            }
        }
        counts[row] = c;
        out_cnt[row] = (float)c;
    }

    int r[KSEL];
#pragma unroll
    for (int q = 0; q < KSEL; q++) r[q] = top8[q];

    // mask row: coalesced float4 writes (overlaps with this kernel's read BW)
    float4* mrow = reinterpret_cast<float4*>(mask_out + (size_t)row * SDIM);
    for (int k = 0; k < 8; k++) {
        int f4 = t + k * 256;
        int jb = f4 * 4;
        float4 o;
        float* op = &o.x;
#pragma unroll
        for (int e = 0; e < 4; e++) {
            int j = jb + e;
            bool b = full || (j < GTOK) || (j >= wlo && j <= whi);
#pragma unroll
            for (int q = 0; q < KSEL; q++) b = b || (j == r[q]);
            op[e] = b ? 1.0f : 0.0f;
        }
        mrow[f4] = o;
    }
}

// ---------------- exact fallback for flagged rows (data-independence guard;
// never fires for the fixed input)
__global__ __launch_bounds__(64) void fallback_kernel(const float* __restrict__ scores,
                                                      int* __restrict__ rand_idx,
                                                      const int* __restrict__ flags,
                                                      int* __restrict__ counts,
                                                      float* __restrict__ out_cnt,
                                                      float* __restrict__ mask_out) {
    __shared__ int s_top[KSEL];
    const int base = blockIdx.x * 64;
    const int t = threadIdx.x;
    unsigned long long m = __ballot(flags[base + t] != 0);
    if (m == 0ull) return;
    for (int b = 0; b < 64; b++) {
        if (!((m >> b) & 1ull)) continue;
        const int row = base + b;
        int wlo = row - RAD; if (wlo < 0) wlo = 0;
        int whi = row + RAD; if (whi > SDIM - 1) whi = SDIM - 1;
        const bool full = row < GTOK;
        if (t == 0) {
            const float* rp = scores + (size_t)row * SDIM;
            int chosen[KSEL];
            for (int round = 0; round < KSEL; round++) {
                float bv = -INFINITY; int bi = 0x7fffffff;
                for (int j = 0; j < SDIM; j++) {
                    bool used = false;
                    for (int q = 0; q < round; q++) used = used || (chosen[q] == j);
                    float val = rp[j];
                    if (!used && val > bv) { bv = val; bi = j; }
                }
                chosen[round] = bi;
                s_top[round] = bi;
                rand_idx[row * KSEL + round] = bi;
            }
            int c;
            if (full) c = SDIM;
            else {
                c = (whi - wlo + 1) + (wlo < GTOK ? wlo : GTOK);
                for (int q = 0; q < KSEL; q++) {
                    int r = chosen[q];
                    if (r >= GTOK && (r < wlo || r > whi)) c++;
                }
            }
            counts[row] = c;
            out_cnt[row] = (float)c;
        }
        __syncthreads();
        int r[KSEL];
        for (int q = 0; q < KSEL; q++) r[q] = s_top[q];
        float4* mrow = reinterpret_cast<float4*>(mask_out + (size_t)row * SDIM);
        for (int f4 = t; f4 < SDIM / 4; f4 += 64) {
            int jb = f4 * 4;
            float4 o; float* op = &o.x;
            for (int e = 0; e < 4; e++) {
                int j = jb + e;
                bool bb = full || (j < GTOK) || (j >= wlo && j <= whi);
                for (int q = 0; q < KSEL; q++) bb = bb || (j == r[q]);
                op[e] = bb ? 1.0f : 0.0f;
            }
            mrow[f4] = o;
        }
        __syncthreads();
    }
}

// --------------------------------------------- scan counts -> offsets (1 block)
__global__ __launch_bounds__(1024) void scan_kernel(const int* __restrict__ counts,
                                                    int* __restrict__ offsets,
                                                    float* __restrict__ out_off,
                                                    float* __restrict__ out_sparsity) {
    __shared__ int part[1024];
    const int t = threadIdx.x;
    const int base = t * 8;
    int local[8], cnts[8];
    int sum = 0;
#pragma unroll
    for (int e = 0; e < 8; e++) {
        cnts[e] = counts[base + e];
        local[e] = sum;
        sum += cnts[e];
    }
    part[t] = sum;
    __syncthreads();
    for (int d = 1; d < 1024; d <<= 1) {
        int add = (t >= d) ? part[t - d] : 0;
        __syncthreads();
        part[t] += add;
        __syncthreads();
    }
    const int excl = (t == 0) ? 0 : part[t - 1];
#pragma unroll
    for (int e = 0; e < 8; e++) {
        int off = excl + local[e];
        offsets[base + e] = off;
        out_off[base + e] = (float)off;
    }
    if (t == 1023) {
        int total = part[1023];
        offsets[SDIM] = total;
        out_off[SDIM] = (float)total;
        *out_sparsity = (float)total / 67108864.0f;   // total < 2^24 -> exact
    }
}

// ------------------------------------------------------------- col_indices fill
__global__ __launch_bounds__(256) void col_kernel(const int* __restrict__ rand_idx,
                                                  const int* __restrict__ offsets,
                                                  float* __restrict__ col_out) {
    __shared__ int cs[256];
    const int row = blockIdx.x;
    const int t   = threadIdx.x;
    int r[KSEL];
#pragma unroll
    for (int q = 0; q < KSEL; q++) r[q] = rand_idx[row * KSEL + q];
    const bool full = row < GTOK;
    int wlo = row - RAD; if (wlo < 0) wlo = 0;
    int whi = row + RAD; if (whi > SDIM - 1) whi = SDIM - 1;

    const int jb = t * 32;
    unsigned int bm;
    if (full || jb + 31 < GTOK) {
        bm = ~0u;                         // global row, or cols 0..63 (t<2)
    } else {
        bm = 0u;
        int lo = wlo > jb ? wlo : jb;
        int hi = whi < jb + 31 ? whi : jb + 31;
        if (lo <= hi) {
            int a = lo - jb, z = hi - jb;
            unsigned hiM = (z == 31) ? ~0u : ((1u << (z + 1)) - 1u);
            unsigned loM = (1u << a) - 1u;
            bm = hiM & ~loM;
        }
#pragma unroll
        for (int q = 0; q < KSEL; q++)
            if ((r[q] >> 5) == t) bm |= 1u << (r[q] & 31);
    }
    cs[t] = __popc(bm);
    __syncthreads();
    for (int d = 1; d < 256; d <<= 1) {
        int add = (t >= d) ? cs[t - d] : 0;
        __syncthreads();
        cs[t] += add;
        __syncthreads();
    }
    int pos = offsets[row] + ((t == 0) ? 0 : cs[t - 1]);
    for (int e = 0; e < 32; e++) {
        if ((bm >> e) & 1u) col_out[pos++] = (float)(jb + e);
    }
}

extern "C" void kernel_launch(void* const* d_in, const int* in_sizes, int n_in,
                              void* d_out, int out_size, void* d_ws, size_t ws_size,
                              hipStream_t stream) {
    const float* scores = (const float*)d_in[1];   // rand_scores [S,S] f32

    float* out_f    = (float*)d_out;
    float* mask_out = out_f;                                   // S*S
    float* off_out  = out_f + (size_t)SDIM * SDIM;             // S+1
    float* col_out  = off_out + (SDIM + 1);                    // TC
    const long long TC = (long long)out_size
                       - ((long long)SDIM * SDIM + (SDIM + 1) + SDIM + 1);
    float* cnt_out = col_out + TC;                             // S
    float* sp_out  = cnt_out + SDIM;                           // 1

    int* rand_idx = (int*)d_ws;                  // S*K ints
    int* offsets  = rand_idx + SDIM * KSEL;      // S+1 ints
    int* flags    = offsets + (SDIM + 1);        // S ints
    int* counts   = flags + SDIM;                // S ints

    fused_kernel<<<SDIM, 256, 0, stream>>>(scores, rand_idx, flags, counts, cnt_out, mask_out);
    fallback_kernel<<<SDIM / 64, 64, 0, stream>>>(scores, rand_idx, flags, counts, cnt_out, mask_out);
    scan_kernel<<<1, 1024, 0, stream>>>(counts, offsets, off_out, sp_out);
    col_kernel<<<SDIM, 256, 0, stream>>>(rand_idx, offsets, col_out);
}